// Round 1
// baseline (609.332 us; speedup 1.0000x reference)
//
#include <hip/hip_runtime.h>
#include <hip/hip_bf16.h>

// QuantizedLinear: out[M,N] = (x[M,K] @ W^T) * scale + bias, W[N,K] = q - zp
// M = 4*2048 = 8192, N = 4096, K = 4096.
// Strategy: exact bf16 weights (|q-zp| < 256 -> exact), bf16 x (rounding error
// ~0.3 max vs threshold 5.04), m97-structure MFMA GEMM (128x128x32 tile,
// global_load_lds width=16, 16x16x32 bf16 MFMA, fp32 accumulate).

typedef __bf16 bf16x8 __attribute__((ext_vector_type(8)));
typedef float  f32x4  __attribute__((ext_vector_type(4)));

#define BM 128
#define BN 128
#define BK 32

// ---------------- conversion kernels ----------------

__global__ __launch_bounds__(256) void cvt_x_bf16(
    const float4* __restrict__ x, uint4* __restrict__ o, int n8) {
  int i = blockIdx.x * 256 + threadIdx.x;
  if (i >= n8) return;
  float4 a = x[2 * i];
  float4 b = x[2 * i + 1];
  union { __bf16 h[8]; uint4 u; } r;
  r.h[0] = (__bf16)a.x; r.h[1] = (__bf16)a.y;
  r.h[2] = (__bf16)a.z; r.h[3] = (__bf16)a.w;
  r.h[4] = (__bf16)b.x; r.h[5] = (__bf16)b.y;
  r.h[6] = (__bf16)b.z; r.h[7] = (__bf16)b.w;
  o[i] = r.u;
}

__global__ __launch_bounds__(256) void cvt_w_bf16(
    const int4* __restrict__ q, const int* __restrict__ zp,
    uint4* __restrict__ o, int n8) {
  int i = blockIdx.x * 256 + threadIdx.x;
  if (i >= n8) return;
  int z = zp[0];
  int4 a = q[2 * i];
  int4 b = q[2 * i + 1];
  union { __bf16 h[8]; uint4 u; } r;
  r.h[0] = (__bf16)(float)(a.x - z); r.h[1] = (__bf16)(float)(a.y - z);
  r.h[2] = (__bf16)(float)(a.z - z); r.h[3] = (__bf16)(float)(a.w - z);
  r.h[4] = (__bf16)(float)(b.x - z); r.h[5] = (__bf16)(float)(b.y - z);
  r.h[6] = (__bf16)(float)(b.z - z); r.h[7] = (__bf16)(float)(b.w - z);
  o[i] = r.u;
}

// ---------------- GEMM (m97 structure) ----------------
// A[M,K] bf16 row-major, Bw[N,K] bf16 row-major (i.e. B^T, K-contiguous).
// C[M,N] fp32 = scale * (A @ Bw^T) + bias.

__global__ __launch_bounds__(256) void gemm_bt(
    const __bf16* __restrict__ A, const __bf16* __restrict__ Bw,
    const float* __restrict__ scale, const float* __restrict__ bias,
    float* __restrict__ C, int M, int N, int K) {
  __shared__ __bf16 As[BM * BK];
  __shared__ __bf16 Bs[BN * BK];

  const int tid  = threadIdx.x;
  const int wave = tid >> 6;
  const int lane = tid & 63;

  const int m0 = blockIdx.y * BM;
  const int n0 = blockIdx.x * BN;

  // staging: each wave fills 32 rows (two global_load_lds calls of 16 rows).
  // lane -> row (lane>>2), 16B chunk (lane&3) within the 64B row.
  const int s_row = lane >> 2;          // 0..15
  const int s_col = (lane & 3) * 8;     // element offset: 0,8,16,24

  const __bf16* Ag = A  + (size_t)(m0 + wave * 32 + s_row) * K + s_col;
  const __bf16* Bg = Bw + (size_t)(n0 + wave * 32 + s_row) * K + s_col;
  __bf16* Asl = As + (wave * 32) * BK;  // wave-uniform LDS base
  __bf16* Bsl = Bs + (wave * 32) * BK;

  // compute mapping: 2x2 waves of 64x64; 4x4 fragments of 16x16 each.
  const int wm   = (wave >> 1) * 64;
  const int wn   = (wave & 1) * 64;
  const int fr   = lane & 15;   // fragment row (A) / col (B,C)
  const int quad = lane >> 4;   // 0..3

  f32x4 acc[4][4] = {};

  for (int k0 = 0; k0 < K; k0 += BK) {
    __builtin_amdgcn_global_load_lds(
        (const __attribute__((address_space(1))) void*)(Ag + k0),
        (__attribute__((address_space(3))) void*)(Asl), 16, 0, 0);
    __builtin_amdgcn_global_load_lds(
        (const __attribute__((address_space(1))) void*)(Ag + (size_t)16 * K + k0),
        (__attribute__((address_space(3))) void*)(Asl + 16 * BK), 16, 0, 0);
    __builtin_amdgcn_global_load_lds(
        (const __attribute__((address_space(1))) void*)(Bg + k0),
        (__attribute__((address_space(3))) void*)(Bsl), 16, 0, 0);
    __builtin_amdgcn_global_load_lds(
        (const __attribute__((address_space(1))) void*)(Bg + (size_t)16 * K + k0),
        (__attribute__((address_space(3))) void*)(Bsl + 16 * BK), 16, 0, 0);
    __syncthreads();

    bf16x8 af[4], bfr[4];
#pragma unroll
    for (int i = 0; i < 4; i++)
      af[i] = *(const bf16x8*)(As + (wm + i * 16 + fr) * BK + quad * 8);
#pragma unroll
    for (int j = 0; j < 4; j++)
      bfr[j] = *(const bf16x8*)(Bs + (wn + j * 16 + fr) * BK + quad * 8);

#pragma unroll
    for (int i = 0; i < 4; i++)
#pragma unroll
      for (int j = 0; j < 4; j++)
        acc[i][j] = __builtin_amdgcn_mfma_f32_16x16x32_bf16(
            af[i], bfr[j], acc[i][j], 0, 0, 0);
    __syncthreads();
  }

  // epilogue: C/D layout col = lane&15, row = quad*4 + reg (m89-verified)
  const float s = scale[0];
#pragma unroll
  for (int i = 0; i < 4; i++) {
    const int row = m0 + wm + i * 16 + quad * 4;
#pragma unroll
    for (int j = 0; j < 4; j++) {
      const int col = n0 + wn + j * 16 + fr;
      const float bv = bias[col];
      float* cp = C + (size_t)row * N + col;
#pragma unroll
      for (int r = 0; r < 4; r++)
        cp[(size_t)r * N] = s * acc[i][j][r] + bv;
    }
  }
}

// ---------------- launch ----------------

extern "C" void kernel_launch(void* const* d_in, const int* in_sizes, int n_in,
                              void* d_out, int out_size, void* d_ws, size_t ws_size,
                              hipStream_t stream) {
  const int M = 8192, N = 4096, K = 4096;

  const float* x    = (const float*)d_in[0];
  const int*   qw   = (const int*)d_in[1];
  const int*   zp   = (const int*)d_in[2];
  const float* sc   = (const float*)d_in[3];
  const float* bias = (const float*)d_in[4];
  float* out = (float*)d_out;

  // workspace layout: [0, 64MB) x_bf16, [64MB, 96MB) w_bf16
  __bf16* x_bf = (__bf16*)d_ws;
  __bf16* w_bf = (__bf16*)((char*)d_ws + (size_t)M * K * sizeof(__bf16));

  {
    int n8 = (M * K) / 8;  // 4,194,304
    cvt_x_bf16<<<n8 / 256, 256, 0, stream>>>((const float4*)x, (uint4*)x_bf, n8);
  }
  {
    int n8 = (N * K) / 8;  // 2,097,152
    cvt_w_bf16<<<n8 / 256, 256, 0, stream>>>((const int4*)qw, zp, (uint4*)w_bf, n8);
  }

  dim3 grid(N / BN, M / BM);  // (32, 64)
  gemm_bt<<<grid, 256, 0, stream>>>(x_bf, w_bf, sc, bias, out, M, N, K);
}